// Round 7
// baseline (131.648 us; speedup 1.0000x reference)
//
#include <hip/hip_runtime.h>
#include <hip/hip_bf16.h>

// SnakeBrain fused kernel, round 7: packed-fp32 (v_pk_fma_f32) issue-slot cut.
// R6 post-mortem: R5 (DS-heavy) == R6 (barrier-free) == ~30us -> VALU-issue
// bound; scalar v_fma_f32 is HALF rate on CDNA4 (157TF needs VOP3P packed).
// This round: float2-vectorize r1/split/stencil2/pool/head k-loops (same fma
// semantics, ~45% fewer VALU slots). Structure identical to verified R6:
// one wave = one snake, rolling 3-tile window, zero __syncthreads.

#define NB  4096
#define CL  256
#define HID 32
#define FIN 64

typedef __attribute__((ext_vector_type(8))) short    bf16x8;
typedef __attribute__((ext_vector_type(4))) float    f32x4;
typedef __attribute__((ext_vector_type(2))) float    f32x2;
typedef __attribute__((ext_vector_type(4))) unsigned u32x4;

__device__ __forceinline__ unsigned pkbf(float a, float b) {
    // packs bf16(a) low 16, bf16(b) high 16 (RNE, v_cvt_pk_bf16_f32)
    __hip_bfloat162 hb = __float22bfloat162_rn(make_float2(a, b));
    unsigned u; __builtin_memcpy(&u, &hb, sizeof(u));
    return u;
}
__device__ __forceinline__ float bflo(unsigned u) { return __builtin_bit_cast(float, u << 16); }
__device__ __forceinline__ float bfhi(unsigned u) { return __builtin_bit_cast(float, u & 0xffff0000u); }

__device__ __forceinline__ f32x2 sfma(float s, f32x2 v, f32x2 a) {
    f32x2 sv = {s, s};
    return __builtin_elementwise_fma(sv, v, a);
}
__device__ __forceinline__ f32x2 vfma(f32x2 x, f32x2 y, f32x2 a) {
    return __builtin_elementwise_fma(x, y, a);
}
__device__ __forceinline__ f32x2 smul(float s, f32x2 v) { f32x2 sv = {s, s}; return sv * v; }
__device__ __forceinline__ f32x2 vmax0(f32x2 v) {
    f32x2 z = {0.f, 0.f};
    return __builtin_elementwise_max(v, z);
}

// GCN chain coefficients for node n (deg incl self-loop: 3 interior, 2 ends)
__device__ __forceinline__ void gcn_coef(int n, float& nc, float& nl, float& nr) {
    const float IS3 = 0.57735026918962576f, IS2 = 0.70710678118654752f;
    const float dn = (n == 0 || n == CL - 1) ? IS2 : IS3;
    nc = dn * dn;
    nl = (n > 0)      ? dn * ((n == 1)      ? IS2 : IS3) : 0.0f;
    nr = (n < CL - 1) ? dn * ((n == CL - 2) ? IS2 : IS3) : 0.0f;
}

__global__ __launch_bounds__(256, 4) void snake_fused(
    const float* __restrict__ x,
    const float* __restrict__ heads,
    const float* __restrict__ body_sizes,
    const float* __restrict__ fruits,
    const float* __restrict__ W1, const float* __restrict__ b1,
    const float* __restrict__ W2, const float* __restrict__ b2,
    const float* __restrict__ Wr, const float* __restrict__ br,
    const float* __restrict__ Wa1, const float* __restrict__ ba1,
    const float* __restrict__ Wa2, const float* __restrict__ ba2,
    const float* __restrict__ Wc, const float* __restrict__ bc,
    const float* __restrict__ Wp, const float* __restrict__ bp,
    const float* __restrict__ Wv, const float* __restrict__ bv,
    float* __restrict__ out)
{
    // per-wave scratch, never cross-wave -> no barriers anywhere.
    __shared__ __align__(16) float wsc[4][FIN];

    const int tid  = threadIdx.x;
    const int w    = tid >> 6;
    const int lane = tid & 63;
    const int g    = lane >> 4;     // k-group (A) / row-group (C)
    const int c    = lane & 15;     // tile col / m within tile
    const int gs   = blockIdx.x * 4 + w;   // this wave's snake

    // ---- B fragments for W2 (split bf16): B[k=8g+j][n=c+16nt] ----
    bf16x8 Bh[2], Bl[2];
    #pragma unroll
    for (int nt = 0; nt < 2; ++nt) {
        unsigned hh[4], ll[4];
        #pragma unroll
        for (int p = 0; p < 4; ++p) {
            const float wa = W2[(8 * g + 2 * p)     * HID + c + 16 * nt];
            const float wb = W2[(8 * g + 2 * p + 1) * HID + c + 16 * nt];
            const unsigned hu = pkbf(wa, wb);
            hh[p] = hu;
            ll[p] = pkbf(wa - bflo(hu), wb - bfhi(hu));
        }
        u32x4 H = {hh[0], hh[1], hh[2], hh[3]};
        u32x4 L = {ll[0], ll[1], ll[2], ll[3]};
        Bh[nt] = __builtin_bit_cast(bf16x8, H);
        Bl[nt] = __builtin_bit_cast(bf16x8, L);
    }
    const f32x2 bb2 = {b2[c], b2[c + 16]};

    // W1/b1 channel-pair slices for this lane's A-channels 8g..8g+7
    const float4 W1a0 = *(const float4*)(W1 + 8 * g);
    const float4 W1a1 = *(const float4*)(W1 + 8 * g + 4);
    const float4 W1b0 = *(const float4*)(W1 + HID + 8 * g);
    const float4 W1b1 = *(const float4*)(W1 + HID + 8 * g + 4);
    const float4 b1v0 = *(const float4*)(b1 + 8 * g);
    const float4 b1v1 = *(const float4*)(b1 + 8 * g + 4);
    const f32x2 W1ap[4] = {{W1a0.x, W1a0.y}, {W1a0.z, W1a0.w}, {W1a1.x, W1a1.y}, {W1a1.z, W1a1.w}};
    const f32x2 W1bp[4] = {{W1b0.x, W1b0.y}, {W1b0.z, W1b0.w}, {W1b1.x, W1b1.y}, {W1b1.z, W1b1.w}};
    const f32x2 b1p[4]  = {{b1v0.x, b1v0.y}, {b1v0.z, b1v0.w}, {b1v1.x, b1v1.y}, {b1v1.z, b1v1.w}};

    const float THIRD = 0.33333333333333333f;
    const float I23   = 0.40824829046386302f;   // 1/sqrt(6)

    const float2* xs = (const float2*)x + gs * CL;

    // tile t: nodes 16t..16t+15. Lane supplies A[m=c][k=8g+j] (ch 8g..8g+7 of
    // node 16t+c). Stencil-1 done on x directly (S and W1 commute).
    auto compute_tile = [&](int t, f32x4* accT) {
        const int m = 16 * t + c;
        const float2 xcv = xs[m];
        const float2 xlv = xs[m - (m > 0)];
        const float2 xrv = xs[m + (m < CL - 1)];
        float ncd = THIRD, nld = THIRD, nrd = THIRD;
        if (t == 0 || t == 15) gcn_coef(m, ncd, nld, nrd);
        const f32x2 xc2 = {xcv.x, xcv.y};
        const f32x2 xl2 = {xlv.x, xlv.y};
        const f32x2 xr2 = {xrv.x, xrv.y};
        const f32x2 s2 = sfma(ncd, xc2, sfma(nld, xl2, smul(nrd, xr2)));
        const f32x2 sav = {s2.x, s2.x};
        const f32x2 sbv = {s2.y, s2.y};
        unsigned HH[4], LL[4];
        #pragma unroll
        for (int p = 0; p < 4; ++p) {
            const f32x2 r = vmax0(vfma(sav, W1ap[p], vfma(sbv, W1bp[p], b1p[p])));
            const unsigned h = pkbf(r.x, r.y);
            const f32x2 hf = {bflo(h), bfhi(h)};
            const f32x2 lo = r - hf;
            HH[p] = h;
            LL[p] = pkbf(lo.x, lo.y);
        }
        u32x4 HU = {HH[0], HH[1], HH[2], HH[3]};
        u32x4 LU = {LL[0], LL[1], LL[2], LL[3]};
        const bf16x8 ah = __builtin_bit_cast(bf16x8, HU);
        const bf16x8 al = __builtin_bit_cast(bf16x8, LU);
        #pragma unroll
        for (int nt = 0; nt < 2; ++nt) {
            f32x4 a0 = {0.f, 0.f, 0.f, 0.f};
            a0 = __builtin_amdgcn_mfma_f32_16x16x32_bf16(ah, Bh[nt], a0, 0, 0, 0);
            a0 = __builtin_amdgcn_mfma_f32_16x16x32_bf16(al, Bh[nt], a0, 0, 0, 0);
            a0 = __builtin_amdgcn_mfma_f32_16x16x32_bf16(ah, Bl[nt], a0, 0, 0, 0);
            accT[nt] = a0;
        }
    };

    // ---- main loop: rolling 3-tile window, no barriers ----
    // C/D: lane holds rows 16t+4g+{0..3}, cols {c, c+16}; nt-paired f32x2 math.
    f32x4 accC[2], accN[2];
    { f32x4 z = {0.f, 0.f, 0.f, 0.f}; accN[0] = z; accN[1] = z; }
    compute_tile(0, accC);
    f32x2 p3 = {0.f, 0.f};          // prev tile's reg3 pair (consumed masked at t=0)
    f32x2 sum2 = {0.f, 0.f};

    #pragma unroll
    for (int t = 0; t < 16; ++t) {
        if (t < 15) compute_tile(t + 1, accN);
        const bool fL = (t == 0)  && (g == 0);
        const bool fR = (t == 15) && (g == 3);
        const float c0  = fL ? 0.5f : THIRD;
        const float r0c = fL ? I23  : THIRD;
        const float l1c = fL ? I23  : THIRD;
        const float c3  = fR ? 0.5f : THIRD;
        const float l3c = fR ? I23  : THIRD;
        const float r2c = fR ? I23  : THIRD;

        const f32x2 v0 = {accC[0][0], accC[1][0]};
        const f32x2 v1 = {accC[0][1], accC[1][1]};
        const f32x2 v2 = {accC[0][2], accC[1][2]};
        const f32x2 v3 = {accC[0][3], accC[1][3]};

        // left neighbor of reg0: sender g==3 provides prev tile's reg3
        const f32x2 Lsend = (g == 3) ? p3 : v3;
        const int   Lsrc  = (g == 0) ? (c + 48) : (lane - 16);
        f32x2 L = {__shfl(Lsend.x, Lsrc, 64), __shfl(Lsend.y, Lsrc, 64)};
        if (t == 0) { L.x = (g == 0) ? 0.f : L.x; L.y = (g == 0) ? 0.f : L.y; }
        // right neighbor of reg3: sender g==0 provides next tile's reg0
        const f32x2 n0 = {accN[0][0], accN[1][0]};
        const f32x2 Rsend = (g == 0) ? n0 : v0;
        const int   Rsrc  = (g == 3) ? c : (lane + 16);
        f32x2 R = {__shfl(Rsend.x, Rsrc, 64), __shfl(Rsend.y, Rsrc, 64)};
        if (t == 15) { R.x = (g == 3) ? 0.f : R.x; R.y = (g == 3) ? 0.f : R.y; }

        const f32x2 h0 = vmax0(sfma(c0,    v0, sfma(THIRD, L,  sfma(r0c,   v1, bb2))));
        const f32x2 h1 = vmax0(sfma(THIRD, v1, sfma(l1c,   v0, sfma(THIRD, v2, bb2))));
        const f32x2 h2 = vmax0(sfma(THIRD, v2, sfma(THIRD, v1, sfma(r2c,   v3, bb2))));
        const f32x2 h3 = vmax0(sfma(c3,    v3, sfma(l3c,   v2, sfma(THIRD, R,  bb2))));
        sum2 += (h0 + h1) + (h2 + h3);

        p3 = v3;
        accC[0] = accN[0]; accC[1] = accN[1];
    }

    // ---- mean pool: butterfly over the 4 row-groups (bits 4,5) ----
    {
        f32x2 tmp = {__shfl_xor(sum2.x, 16, 64), __shfl_xor(sum2.y, 16, 64)};
        sum2 += tmp;
        f32x2 tmp2 = {__shfl_xor(sum2.x, 32, 64), __shfl_xor(sum2.y, 32, 64)};
        sum2 += tmp2;
    }
    wsc[w][c]      = sum2.x * (1.0f / CL);   // convergent (4 lanes, same value)
    wsc[w][c + 16] = sum2.y * (1.0f / CL);

    // ---- head (per wave, own snake; in-order same-wave DS, no barriers) ----
    if (lane >= 32) {     // aux1 in lanes 32-63
        const int cc = lane - 32;
        float a = ba1[cc];
        a = fmaf(heads[2 * gs],      Wa1[0 * HID + cc], a);
        a = fmaf(heads[2 * gs + 1],  Wa1[1 * HID + cc], a);
        a = fmaf(body_sizes[gs],     Wa1[2 * HID + cc], a);
        a = fmaf(fruits[2 * gs],     Wa1[3 * HID + cc], a);
        a = fmaf(fruits[2 * gs + 1], Wa1[4 * HID + cc], a);
        wsc[w][32 + cc] = fmaxf(a, 0.f);
    }
    // merged convergent stage: lanes 0-31 body_emb (no relu), 32-63 aux2 (relu)
    {
        const int  hh = lane >> 5;
        const int  cc = lane & 31;
        const float* Wsel = hh ? Wa2 : Wr;
        const float  bsel = hh ? ba2[cc] : br[cc];
        const float* lsel = &wsc[w][32 * hh];
        f32x2 cv2 = {bsel, 0.f};
        #pragma unroll
        for (int k4 = 0; k4 < 8; ++k4) {
            const f32x4 p = *(const f32x4*)&lsel[4 * k4];   // broadcast b128
            const f32x2 p01 = {p[0], p[1]};
            const f32x2 p23 = {p[2], p[3]};
            const f32x2 w01 = {Wsel[(4 * k4 + 0) * HID + cc], Wsel[(4 * k4 + 1) * HID + cc]};
            const f32x2 w23 = {Wsel[(4 * k4 + 2) * HID + cc], Wsel[(4 * k4 + 3) * HID + cc]};
            cv2 = vfma(p01, w01, cv2);
            cv2 = vfma(p23, w23, cv2);
        }
        float cv = cv2.x + cv2.y;
        cv = hh ? fmaxf(cv, 0.f) : cv;
        wsc[w][lane] = cv;    // cat; same-wave in-order DS
    }
    // combined = relu(cat @ Wc + bc), then logits/value butterfly
    {
        f32x2 cb2 = {bc[lane], 0.f};
        #pragma unroll
        for (int k4 = 0; k4 < 16; ++k4) {
            const f32x4 p = *(const f32x4*)&wsc[w][4 * k4];
            const f32x2 p01 = {p[0], p[1]};
            const f32x2 p23 = {p[2], p[3]};
            const f32x2 w01 = {Wc[(4 * k4 + 0) * FIN + lane], Wc[(4 * k4 + 1) * FIN + lane]};
            const f32x2 w23 = {Wc[(4 * k4 + 2) * FIN + lane], Wc[(4 * k4 + 3) * FIN + lane]};
            cb2 = vfma(p01, w01, cb2);
            cb2 = vfma(p23, w23, cb2);
        }
        const float cb = fmaxf(cb2.x + cb2.y, 0.f);
        float s0 = cb * Wp[lane * 5 + 0];
        float s1 = cb * Wp[lane * 5 + 1];
        float s2 = cb * Wp[lane * 5 + 2];
        float s3 = cb * Wp[lane * 5 + 3];
        float s4 = cb * Wp[lane * 5 + 4];
        float s5 = cb * Wv[lane];
        #pragma unroll
        for (int m = 1; m <= 32; m <<= 1) {
            s0 += __shfl_xor(s0, m, 64);
            s1 += __shfl_xor(s1, m, 64);
            s2 += __shfl_xor(s2, m, 64);
            s3 += __shfl_xor(s3, m, 64);
            s4 += __shfl_xor(s4, m, 64);
            s5 += __shfl_xor(s5, m, 64);
        }
        if (lane == 0) {
            out[gs * 5 + 0] = s0 + bp[0];
            out[gs * 5 + 1] = s1 + bp[1];
            out[gs * 5 + 2] = s2 + bp[2];
            out[gs * 5 + 3] = s3 + bp[3];
            out[gs * 5 + 4] = s4 + bp[4];
            out[NB * 5 + gs] = s5 + bv[0];
        }
    }
}

extern "C" void kernel_launch(void* const* d_in, const int* in_sizes, int n_in,
                              void* d_out, int out_size, void* d_ws, size_t ws_size,
                              hipStream_t stream) {
    const float* x          = (const float*)d_in[0];
    const float* heads      = (const float*)d_in[1];
    const float* body_sizes = (const float*)d_in[2];
    const float* fruits     = (const float*)d_in[3];
    const float* W1 = (const float*)d_in[4];
    const float* b1 = (const float*)d_in[5];
    const float* W2 = (const float*)d_in[6];
    const float* b2 = (const float*)d_in[7];
    const float* Wr = (const float*)d_in[8];
    const float* br = (const float*)d_in[9];
    const float* Wa1 = (const float*)d_in[10];
    const float* ba1 = (const float*)d_in[11];
    const float* Wa2 = (const float*)d_in[12];
    const float* ba2 = (const float*)d_in[13];
    const float* Wc = (const float*)d_in[14];
    const float* bc = (const float*)d_in[15];
    const float* Wp = (const float*)d_in[16];
    const float* bp = (const float*)d_in[17];
    const float* Wv = (const float*)d_in[18];
    const float* bv = (const float*)d_in[19];

    float* out = (float*)d_out;
    snake_fused<<<NB / 4, 256, 0, stream>>>(
        x, heads, body_sizes, fruits,
        W1, b1, W2, b2, Wr, br, Wa1, ba1, Wa2, ba2,
        Wc, bc, Wp, bp, Wv, bv, out);
}